// Round 11
// baseline (142.465 us; speedup 1.0000x reference)
//
#include <hip/hip_runtime.h>
#include <cstdint>

#define SEQ_LEN 2048
#define DIM 1024
#define NHEAD 16
#define DHEAD 64
#define QKV_LD (3 * DIM)

typedef unsigned short u16;
typedef short bf16x8 __attribute__((ext_vector_type(8)));
typedef float f32x4 __attribute__((ext_vector_type(4)));

__device__ __forceinline__ u16 f2bf(float f) {
    union { float f; unsigned u; } v;
    v.f = f;
    unsigned r = v.u + 0x7fff + ((v.u >> 16) & 1);  // RNE
    return (u16)(r >> 16);
}

// async global -> LDS, 16 B per lane (global_load_lds_dwordx4)
__device__ __forceinline__ void load_lds16(const void* g, void* l) {
    __builtin_amdgcn_global_load_lds(
        (const __attribute__((address_space(1))) void*)g,
        (__attribute__((address_space(3))) void*)l, 16, 0, 0);
}

// ---------------------------------------------------------------------------
// Fused prep: [0,2048) cast x -> bf16 ; [2048,5120) transpose Wqkv ;
// [5120,6144) transpose Wout. Branch is block-uniform.
// ---------------------------------------------------------------------------
__device__ __forceinline__ void transpose_tile(const float* __restrict__ W,
                                               u16* __restrict__ Wt, int K, int N,
                                               int bx, int by, int t, float (*tile)[33]) {
    const int n0 = bx * 32, k0 = by * 32;
    const int tx = t & 31, ty = t >> 5;  // 32 x 8
#pragma unroll
    for (int i = 0; i < 32; i += 8)
        tile[ty + i][tx] = W[(size_t)(k0 + ty + i) * N + n0 + tx];
    __syncthreads();
#pragma unroll
    for (int i = 0; i < 32; i += 8)
        Wt[(size_t)(n0 + ty + i) * K + k0 + tx] = f2bf(tile[tx][ty + i]);
}

__global__ __launch_bounds__(256) void prep_k(const float* __restrict__ x,
                                              const float* __restrict__ Wqkv,
                                              const float* __restrict__ Wout,
                                              u16* __restrict__ xb,
                                              u16* __restrict__ Wqkvt,
                                              u16* __restrict__ Woutt) {
    __shared__ float tile[32][33];
    const int b = blockIdx.x;
    const int t = threadIdx.x;
    if (b < 2048) {  // cast x
        const int i = b * 256 + t;
        const float4 v = reinterpret_cast<const float4*>(x)[i];
        const unsigned p0 = (unsigned)f2bf(v.x) | ((unsigned)f2bf(v.y) << 16);
        const unsigned p1 = (unsigned)f2bf(v.z) | ((unsigned)f2bf(v.w) << 16);
        reinterpret_cast<uint2*>(xb)[i] = make_uint2(p0, p1);
    } else if (b < 5120) {  // Wqkv [1024,3072] -> [3072,1024]
        const int b2 = b - 2048;
        transpose_tile(Wqkv, Wqkvt, DIM, QKV_LD, b2 % 96, b2 / 96, t, tile);
    } else {  // Wout [1024,1024] -> transposed
        const int b3 = b - 5120;
        transpose_tile(Wout, Woutt, DIM, DIM, b3 & 31, b3 >> 5, t, tile);
    }
}

// ---------------------------------------------------------------------------
// bf16 MFMA GEMM: C = A[M,K] @ Bt[N,K]^T. Tile BM x BN x BK, dbuf DMA LDS,
// one barrier/K-iter. 4 waves: 2(m) x 2(n).
// MODE 0 (QKV producer): writes Q natural [s][1024] PRE-SCALED by
//   0.125*log2(e); K d-group-swizzled [s][1024] (groups of 8 d XORed by
//   s&7); V transposed [hd][2048] with kv-groups XORed by d&7.
// MODE 1: fp32 output + bias.
// ---------------------------------------------------------------------------
template <int MODE, int BM, int BN, int BK>
__global__ __launch_bounds__(256) void gemm_bf16(const u16* __restrict__ A,
                                                 const u16* __restrict__ Bt,
                                                 const float* __restrict__ bias,
                                                 void* __restrict__ Cout,
                                                 u16* __restrict__ kout,
                                                 u16* __restrict__ vout,
                                                 int M, int N, int K) {
    constexpr int AI = BM / 32;
    constexpr int BJ = BN / 32;
    constexpr int ASZ = BM * BK;
    constexpr int BSZ = BN * BK;
    __shared__ u16 As[2 * ASZ];
    __shared__ u16 Bs[2 * BSZ];

    const int t = threadIdx.x;
    const int lane = t & 63;
    const int quad = lane >> 4;
    const int l15 = lane & 15;
    const int w = t >> 6;
    const int wm = (w & 1) * (BM / 2);
    const int wn = (w >> 1) * (BN / 2);
    const int m0 = blockIdx.y * BM;
    const int n0 = blockIdx.x * BN;
    const int sr = t >> 2;
    const int sc = (t & 3) << 3;

    const u16* Ab = A + (size_t)(m0 + sr) * K + sc;
    const u16* Bb = Bt + (size_t)(n0 + sr) * K + sc;

    auto stage = [&](int buf, int k0) {
#pragma unroll
        for (int kc = 0; kc < BK / 32; ++kc) {
#pragma unroll
            for (int c = 0; c < BM / 64; ++c)
                load_lds16(Ab + (size_t)(c * 64) * K + k0 + kc * 32,
                           &As[buf * ASZ + kc * BM * 32 + c * 2048 + t * 8]);
#pragma unroll
            for (int c = 0; c < BN / 64; ++c)
                load_lds16(Bb + (size_t)(c * 64) * K + k0 + kc * 32,
                           &Bs[buf * BSZ + kc * BN * 32 + c * 2048 + t * 8]);
        }
    };

    stage(0, 0);
    f32x4 acc[AI][BJ] = {};

    const int niter = K / BK;
    for (int it = 0; it < niter; ++it) {
        const int cur = it & 1, nxt = cur ^ 1;
        __syncthreads();
        if (it + 1 < niter) stage(nxt, (it + 1) * BK);
#pragma unroll
        for (int kc = 0; kc < BK / 32; ++kc) {
            bf16x8 af[AI], bfr[BJ];
#pragma unroll
            for (int i = 0; i < AI; ++i)
                af[i] = *reinterpret_cast<const bf16x8*>(
                    &As[cur * ASZ + kc * BM * 32 + (wm + i * 16 + l15) * 32 + quad * 8]);
#pragma unroll
            for (int j = 0; j < BJ; ++j)
                bfr[j] = *reinterpret_cast<const bf16x8*>(
                    &Bs[cur * BSZ + kc * BN * 32 + (wn + j * 16 + l15) * 32 + quad * 8]);
#pragma unroll
            for (int i = 0; i < AI; ++i)
#pragma unroll
                for (int j = 0; j < BJ; ++j)
                    acc[i][j] =
                        __builtin_amdgcn_mfma_f32_16x16x32_bf16(af[i], bfr[j], acc[i][j], 0, 0, 0);
        }
    }

    if constexpr (MODE == 1) {
#pragma unroll
        for (int j = 0; j < BJ; ++j) {
            const int col = n0 + wn + j * 16 + l15;
            const float bv = bias[col];
#pragma unroll
            for (int i = 0; i < AI; ++i) {
                const int row = m0 + wm + i * 16 + quad * 4;
#pragma unroll
                for (int r = 0; r < 4; ++r)
                    ((float*)Cout)[(size_t)(row + r) * N + col] = acc[i][j][r] + bv;
            }
        }
    } else {
        // BN=128 tiles: each tile lies wholly inside one 1024-col region
        const int region = n0 >> 10;  // 0=Q, 1=K, 2=V
        if (region == 0) {
            constexpr float SCL = 0.18033688f;  // (1/8)*log2(e), folded into Q
#pragma unroll
            for (int j = 0; j < BJ; ++j) {
                const int col = n0 + wn + j * 16 + l15;
#pragma unroll
                for (int i = 0; i < AI; ++i) {
                    const int row = m0 + wm + i * 16 + quad * 4;
#pragma unroll
                    for (int r = 0; r < 4; ++r)
                        ((u16*)Cout)[(size_t)(row + r) * DIM + col] = f2bf(acc[i][j][r] * SCL);
                }
            }
        } else if (region == 1) {  // K: d-groups swizzled by s&7
#pragma unroll
            for (int j = 0; j < BJ; ++j) {
                const int hd = n0 + wn + j * 16 + l15 - 1024;
                const int d = hd & 63, hb = hd & ~63;
#pragma unroll
                for (int i = 0; i < AI; ++i) {
                    const int row = m0 + wm + i * 16 + quad * 4;
#pragma unroll
                    for (int r = 0; r < 4; ++r) {
                        const int s = row + r;
                        const int pos = hb + ((((d >> 3) ^ (s & 7)) << 3) | (d & 7));
                        kout[(size_t)s * DIM + pos] = f2bf(acc[i][j][r]);
                    }
                }
            }
        } else {  // V^T: [hd][s], kv-groups swizzled by d&7; 4 rows pack -> 8B
#pragma unroll
            for (int j = 0; j < BJ; ++j) {
                const int hd = n0 + wn + j * 16 + l15 - 2048;
#pragma unroll
                for (int i = 0; i < AI; ++i) {
                    const int srow = m0 + wm + i * 16 + quad * 4;
                    const unsigned p0 = (unsigned)f2bf(acc[i][j][0]) |
                                        ((unsigned)f2bf(acc[i][j][1]) << 16);
                    const unsigned p1 = (unsigned)f2bf(acc[i][j][2]) |
                                        ((unsigned)f2bf(acc[i][j][3]) << 16);
                    const int pos = (srow & ~63) + ((((srow >> 3) & 7) ^ (hd & 7)) << 3) +
                                    (srow & 7);
                    *reinterpret_cast<uint2*>(&vout[(size_t)hd * SEQ_LEN + pos]) =
                        make_uint2(p0, p1);
                }
            }
        }
    }
}

// ---------------------------------------------------------------------------
// MFMA causal flash attention, no-max softmax, DMA-only staging, BM=32.
// 1024 blocks (64 q-subtiles x 16 heads), 4-round LPT. LDS 36.5 KB ->
// 4 blocks/CU. 4 waves = 2(q-half of 16) x 2(kv-half of 32); K/V^T dbuf,
// one barrier per kv-tile, DMA prefetch after barrier. Q arrives PRE-SCALED.
// Epilogue combines the two kv-half waves via LDS overlay.
// ---------------------------------------------------------------------------
__global__ __launch_bounds__(256) void attn_mfma(const u16* __restrict__ Qb,
                                                 const u16* __restrict__ Kb,
                                                 const u16* __restrict__ Vg,
                                                 u16* __restrict__ O) {
    constexpr int PSTR = 36;
    __shared__ u16 SM[2304 + 8192 + 8192];  // Ps | Ks | Vs = 37376 B
    u16* Ps = SM;                 // [4 w][16 q][PSTR]; prologue: Q [32 q][64 d]
    u16* Ks = SM + 2304;          // [2 buf][64 kv][64 d], d-groups ^ (s&7)
    u16* Vs = SM + 2304 + 8192;   // [2 buf][64 d][64 kv], kv-groups ^ (d&7)
    float* OredF = (float*)SM;           // epilogue overlay [32 q][68]
    float* LredF = (float*)(SM + 4608);  // [32 q] fp32

    const int b = blockIdx.x;
    const int h = b & 15;
    const int hb = b >> 4;  // 0..63
    const int g = hb >> 4, ii = hb & 15;
    const int qt = (g == 0) ? (63 - ii) : (g == 1) ? (32 + ii) : (g == 2) ? (31 - ii) : ii;
    const int q0 = qt * 32;
    const int jmax = qt >> 1;

    const int t = threadIdx.x;
    const int lane = t & 63;
    const int quad = lane >> 4;
    const int l15 = lane & 15;
    const int w = t >> 6;
    const int wq = w >> 1;  // q half (16 rows)
    const int wk = w & 1;   // kv half (32 cols)

    const int drow = t >> 3;       // DMA row within 32-row group
    const int doff = (t & 7) * 8;  // DMA 16B lane offset (u16 units)

    auto stageK = [&](int buf, int j0) {
#pragma unroll
        for (int c = 0; c < 2; ++c)
            load_lds16(Kb + (size_t)(j0 + c * 32 + drow) * DIM + h * DHEAD + doff,
                       &Ks[buf * 4096 + c * 2048 + t * 8]);
    };
    auto stageV = [&](int buf, int j0) {
#pragma unroll
        for (int c = 0; c < 2; ++c)
            load_lds16(Vg + (size_t)(h * DHEAD + c * 32 + drow) * SEQ_LEN + j0 + doff,
                       &Vs[buf * 4096 + c * 2048 + t * 8]);
    };

    // ---- prologue: stage Q (into Ps region), K0, V0 ----
    load_lds16(Qb + (size_t)(q0 + drow) * DIM + h * DHEAD + doff, &SM[t * 8]);
    stageK(0, 0);
    stageV(0, 0);
    __syncthreads();  // all prologue DMA drained

    bf16x8 qf[2];
#pragma unroll
    for (int dc = 0; dc < 2; ++dc)
        qf[dc] = *reinterpret_cast<const bf16x8*>(
            &SM[(wq * 16 + l15) * 64 + dc * 32 + quad * 8]);
    __syncthreads();  // Q reads done before Ps writes

    f32x4 oacc[4] = {};
    float lsum[4] = {};
    u16* Pw = Ps + w * 16 * PSTR;

    for (int jt = 0; jt <= jmax; ++jt) {
        const int cur = jt & 1, nxt = cur ^ 1;
        if (jt > 0) __syncthreads();  // buf[cur] DMA drained; buf[nxt] readers done
        if (jt < jmax) {              // prefetch next tile right after barrier
            stageK(nxt, (jt + 1) * 64);
            stageV(nxt, (jt + 1) * 64);
        }

        // ---- S = Q @ K^T (wave: 16 q x 32 kv) ----
        f32x4 sacc[2] = {};
#pragma unroll
        for (int nn = 0; nn < 2; ++nn)
#pragma unroll
            for (int dc = 0; dc < 2; ++dc) {
                const bf16x8 kf = *reinterpret_cast<const bf16x8*>(
                    &Ks[cur * 4096 + (wk * 32 + nn * 16 + l15) * 64 +
                        (((dc * 4 + quad) ^ (l15 & 7)) << 3)]);
                sacc[nn] = __builtin_amdgcn_mfma_f32_16x16x32_bf16(qf[dc], kf, sacc[nn], 0, 0, 0);
            }

        // ---- no-max softmax (Q pre-scaled); P truncated to bf16 ----
        const bool diag = (jt == jmax);
#pragma unroll
        for (int r = 0; r < 4; ++r) {
            const int rowl = wq * 16 + quad * 4 + r;
            float p0 = sacc[0][r], p1 = sacc[1][r];
            if (diag) {
                const int rowi = ((qt & 1) << 5) + rowl;  // row within diag 64-tile
                if (wk * 32 + l15 > rowi) p0 = -1e30f;
                if (wk * 32 + 16 + l15 > rowi) p1 = -1e30f;
            }
            p0 = exp2f(p0);
            p1 = exp2f(p1);
            lsum[r] += p0 + p1;
            const int pr = (quad * 4 + r) * PSTR;
            Pw[pr + l15] = (u16)(__float_as_uint(p0) >> 16);
            Pw[pr + 16 + l15] = (u16)(__float_as_uint(p1) >> 16);
        }

        // ---- O += P @ V (per-wave Ps; wave's 32-kv slice of V^T) ----
        const bf16x8 pf = *reinterpret_cast<const bf16x8*>(&Pw[l15 * PSTR + quad * 8]);
#pragma unroll
        for (int nd = 0; nd < 4; ++nd) {
            const bf16x8 vf = *reinterpret_cast<const bf16x8*>(
                &Vs[cur * 4096 + (nd * 16 + l15) * 64 +
                    (((wk * 4 + quad) ^ (l15 & 7)) << 3)]);
            oacc[nd] = __builtin_amdgcn_mfma_f32_16x16x32_bf16(pf, vf, oacc[nd], 0, 0, 0);
        }
    }

    // ---- epilogue: reduce lsum over 16 kv-lanes (per wave) ----
#pragma unroll
    for (int r = 0; r < 4; ++r) {
        float l = lsum[r];
#pragma unroll
        for (int off = 1; off < 16; off <<= 1) l += __shfl_xor(l, off, 64);
        lsum[r] = l;
    }
    __syncthreads();  // main-loop LDS dead; overlays safe
    if (wk == 1) {    // publish kv-half partials
#pragma unroll
        for (int r = 0; r < 4; ++r) {
            const int rowl = wq * 16 + quad * 4 + r;
            if (l15 == 0) LredF[rowl] = lsum[r];
#pragma unroll
            for (int nd = 0; nd < 4; ++nd)
                OredF[rowl * 68 + nd * 16 + l15] = oacc[nd][r];
        }
    }
    __syncthreads();
    if (wk == 0) {  // combine, normalize (combined l > 0 always), write bf16
#pragma unroll
        for (int r = 0; r < 4; ++r) {
            const int rowl = wq * 16 + quad * 4 + r;
            const float inv = 1.0f / (lsum[r] + LredF[rowl]);
            const int row = q0 + rowl;
#pragma unroll
            for (int nd = 0; nd < 4; ++nd)
                O[(size_t)row * DIM + h * DHEAD + nd * 16 + l15] =
                    f2bf((oacc[nd][r] + OredF[rowl * 68 + nd * 16 + l15]) * inv);
        }
    }
}

// ---------------------------------------------------------------------------
extern "C" void kernel_launch(void* const* d_in, const int* in_sizes, int n_in,
                              void* d_out, int out_size, void* d_ws, size_t ws_size,
                              hipStream_t stream) {
    const float* x = (const float*)d_in[0];     // [2048,1024]
    const float* Wqkv = (const float*)d_in[1];  // [1024,3072]
    const float* Wout = (const float*)d_in[2];  // [1024,1024]
    const float* bias = (const float*)d_in[3];  // [1024]
    float* out = (float*)d_out;

    char* ws = (char*)d_ws;
    u16* xb = (u16*)ws;                     // 4 MB
    u16* Wqkvt = (u16*)(ws + (4u << 20));   // 6 MB  [3072,1024]
    u16* Woutt = (u16*)(ws + (10u << 20));  // 2 MB  [1024,1024]
    u16* Qb = (u16*)(ws + (12u << 20));     // 4 MB  [2048,1024] pre-scaled
    u16* Kb = (u16*)(ws + (16u << 20));     // 4 MB  [2048,1024] swizzled
    u16* Vg = (u16*)(ws + (20u << 20));     // 4 MB  [1024,2048] V^T swizzled
    u16* Ob = (u16*)(ws + (24u << 20));     // 4 MB  [2048,1024]

    // fused prep: cast x + transpose Wqkv + transpose Wout
    prep_k<<<dim3(6144), 256, 0, stream>>>(x, Wqkv, Wout, xb, Wqkvt, Woutt);

    // qkv = x @ Wqkv: 128x128x64 (m97 sweet-spot ratio, MFMA:ds_read = 2.0)
    // grid 24x16 = 384 blocks; BK=64 halves barrier drains at low occupancy
    gemm_bf16<0, 128, 128, 64><<<dim3(QKV_LD / 128, SEQ_LEN / 128), 256, 0, stream>>>(
        xb, Wqkvt, nullptr, Qb, Kb, Vg, SEQ_LEN, QKV_LD, DIM);

    // causal attention: 1024 blocks (BM=32), 4-round LPT, 4 blocks/CU
    attn_mfma<<<dim3(64 * NHEAD), 256, 0, stream>>>(Qb, Kb, Vg, Ob);

    // out = O @ Wout + bias (fp32): 64x64x64 tiles -> 512 blocks
    gemm_bf16<1, 64, 64, 64><<<dim3(DIM / 64, SEQ_LEN / 64), 256, 0, stream>>>(
        Ob, Woutt, bias, out, nullptr, nullptr, SEQ_LEN, DIM, DIM);
}

// Round 13
// 140.018 us; speedup vs baseline: 1.0175x; 1.0175x over previous
//
#include <hip/hip_runtime.h>
#include <cstdint>

#define SEQ_LEN 2048
#define DIM 1024
#define NHEAD 16
#define DHEAD 64
#define QKV_LD (3 * DIM)

typedef unsigned short u16;
typedef short bf16x8 __attribute__((ext_vector_type(8)));
typedef float f32x4 __attribute__((ext_vector_type(4)));

__device__ __forceinline__ u16 f2bf(float f) {
    union { float f; unsigned u; } v;
    v.f = f;
    unsigned r = v.u + 0x7fff + ((v.u >> 16) & 1);  // RNE
    return (u16)(r >> 16);
}

// async global -> LDS, 16 B per lane (global_load_lds_dwordx4)
__device__ __forceinline__ void load_lds16(const void* g, void* l) {
    __builtin_amdgcn_global_load_lds(
        (const __attribute__((address_space(1))) void*)g,
        (__attribute__((address_space(3))) void*)l, 16, 0, 0);
}

// ---------------------------------------------------------------------------
// Fused prep: [0,2048) cast x -> bf16 ; [2048,5120) transpose Wqkv ;
// [5120,6144) transpose Wout. Branch is block-uniform.
// ---------------------------------------------------------------------------
__device__ __forceinline__ void transpose_tile(const float* __restrict__ W,
                                               u16* __restrict__ Wt, int K, int N,
                                               int bx, int by, int t, float (*tile)[33]) {
    const int n0 = bx * 32, k0 = by * 32;
    const int tx = t & 31, ty = t >> 5;  // 32 x 8
#pragma unroll
    for (int i = 0; i < 32; i += 8)
        tile[ty + i][tx] = W[(size_t)(k0 + ty + i) * N + n0 + tx];
    __syncthreads();
#pragma unroll
    for (int i = 0; i < 32; i += 8)
        Wt[(size_t)(n0 + ty + i) * K + k0 + tx] = f2bf(tile[tx][ty + i]);
}

__global__ __launch_bounds__(256) void prep_k(const float* __restrict__ x,
                                              const float* __restrict__ Wqkv,
                                              const float* __restrict__ Wout,
                                              u16* __restrict__ xb,
                                              u16* __restrict__ Wqkvt,
                                              u16* __restrict__ Woutt) {
    __shared__ float tile[32][33];
    const int b = blockIdx.x;
    const int t = threadIdx.x;
    if (b < 2048) {  // cast x
        const int i = b * 256 + t;
        const float4 v = reinterpret_cast<const float4*>(x)[i];
        const unsigned p0 = (unsigned)f2bf(v.x) | ((unsigned)f2bf(v.y) << 16);
        const unsigned p1 = (unsigned)f2bf(v.z) | ((unsigned)f2bf(v.w) << 16);
        reinterpret_cast<uint2*>(xb)[i] = make_uint2(p0, p1);
    } else if (b < 5120) {  // Wqkv [1024,3072] -> [3072,1024]
        const int b2 = b - 2048;
        transpose_tile(Wqkv, Wqkvt, DIM, QKV_LD, b2 % 96, b2 / 96, t, tile);
    } else {  // Wout [1024,1024] -> transposed
        const int b3 = b - 5120;
        transpose_tile(Wout, Woutt, DIM, DIM, b3 & 31, b3 >> 5, t, tile);
    }
}

// ---------------------------------------------------------------------------
// bf16 MFMA GEMM: C = A[M,K] @ Bt[N,K]^T. Tile BM x BN x BK, dbuf DMA LDS,
// one barrier/K-iter. 4 waves: 2(m) x 2(n).
// MODE 0 (QKV producer): writes Q natural [s][1024]; K d-group-swizzled
//   [s][1024] (groups of 8 d XORed by s&7); V transposed [hd][2048] with
//   kv-groups XORed by d&7 (consumer fragment layouts, DMA-stageable).
// MODE 1: fp32 output + bias.
// ---------------------------------------------------------------------------
template <int MODE, int BM, int BN, int BK>
__global__ __launch_bounds__(256) void gemm_bf16(const u16* __restrict__ A,
                                                 const u16* __restrict__ Bt,
                                                 const float* __restrict__ bias,
                                                 void* __restrict__ Cout,
                                                 u16* __restrict__ kout,
                                                 u16* __restrict__ vout,
                                                 int M, int N, int K) {
    constexpr int AI = BM / 32;
    constexpr int BJ = BN / 32;
    constexpr int ASZ = BM * BK;
    constexpr int BSZ = BN * BK;
    __shared__ u16 As[2 * ASZ];
    __shared__ u16 Bs[2 * BSZ];

    const int t = threadIdx.x;
    const int lane = t & 63;
    const int quad = lane >> 4;
    const int l15 = lane & 15;
    const int w = t >> 6;
    const int wm = (w & 1) * (BM / 2);
    const int wn = (w >> 1) * (BN / 2);
    const int m0 = blockIdx.y * BM;
    const int n0 = blockIdx.x * BN;
    const int sr = t >> 2;
    const int sc = (t & 3) << 3;

    const u16* Ab = A + (size_t)(m0 + sr) * K + sc;
    const u16* Bb = Bt + (size_t)(n0 + sr) * K + sc;

    auto stage = [&](int buf, int k0) {
#pragma unroll
        for (int kc = 0; kc < BK / 32; ++kc) {
#pragma unroll
            for (int c = 0; c < BM / 64; ++c)
                load_lds16(Ab + (size_t)(c * 64) * K + k0 + kc * 32,
                           &As[buf * ASZ + kc * BM * 32 + c * 2048 + t * 8]);
#pragma unroll
            for (int c = 0; c < BN / 64; ++c)
                load_lds16(Bb + (size_t)(c * 64) * K + k0 + kc * 32,
                           &Bs[buf * BSZ + kc * BN * 32 + c * 2048 + t * 8]);
        }
    };

    stage(0, 0);
    f32x4 acc[AI][BJ] = {};

    const int niter = K / BK;
    for (int it = 0; it < niter; ++it) {
        const int cur = it & 1, nxt = cur ^ 1;
        __syncthreads();
        if (it + 1 < niter) stage(nxt, (it + 1) * BK);
#pragma unroll
        for (int kc = 0; kc < BK / 32; ++kc) {
            bf16x8 af[AI], bfr[BJ];
#pragma unroll
            for (int i = 0; i < AI; ++i)
                af[i] = *reinterpret_cast<const bf16x8*>(
                    &As[cur * ASZ + kc * BM * 32 + (wm + i * 16 + l15) * 32 + quad * 8]);
#pragma unroll
            for (int j = 0; j < BJ; ++j)
                bfr[j] = *reinterpret_cast<const bf16x8*>(
                    &Bs[cur * BSZ + kc * BN * 32 + (wn + j * 16 + l15) * 32 + quad * 8]);
#pragma unroll
            for (int i = 0; i < AI; ++i)
#pragma unroll
                for (int j = 0; j < BJ; ++j)
                    acc[i][j] =
                        __builtin_amdgcn_mfma_f32_16x16x32_bf16(af[i], bfr[j], acc[i][j], 0, 0, 0);
        }
    }

    if constexpr (MODE == 1) {
#pragma unroll
        for (int j = 0; j < BJ; ++j) {
            const int col = n0 + wn + j * 16 + l15;
            const float bv = bias[col];
#pragma unroll
            for (int i = 0; i < AI; ++i) {
                const int row = m0 + wm + i * 16 + quad * 4;
#pragma unroll
                for (int r = 0; r < 4; ++r)
                    ((float*)Cout)[(size_t)(row + r) * N + col] = acc[i][j][r] + bv;
            }
        }
    } else {
        const int region = n0 >> 10;  // 0=Q, 1=K, 2=V (BN=64 keeps blocks uniform)
        if (region == 0) {
#pragma unroll
            for (int j = 0; j < BJ; ++j) {
                const int col = n0 + wn + j * 16 + l15;
#pragma unroll
                for (int i = 0; i < AI; ++i) {
                    const int row = m0 + wm + i * 16 + quad * 4;
#pragma unroll
                    for (int r = 0; r < 4; ++r)
                        ((u16*)Cout)[(size_t)(row + r) * DIM + col] = f2bf(acc[i][j][r]);
                }
            }
        } else if (region == 1) {  // K: d-groups swizzled by s&7
#pragma unroll
            for (int j = 0; j < BJ; ++j) {
                const int hd = n0 + wn + j * 16 + l15 - 1024;
                const int d = hd & 63, hb = hd & ~63;
#pragma unroll
                for (int i = 0; i < AI; ++i) {
                    const int row = m0 + wm + i * 16 + quad * 4;
#pragma unroll
                    for (int r = 0; r < 4; ++r) {
                        const int s = row + r;
                        const int pos = hb + ((((d >> 3) ^ (s & 7)) << 3) | (d & 7));
                        kout[(size_t)s * DIM + pos] = f2bf(acc[i][j][r]);
                    }
                }
            }
        } else {  // V^T: [hd][s], kv-groups swizzled by d&7; 4 rows pack -> 8B
#pragma unroll
            for (int j = 0; j < BJ; ++j) {
                const int hd = n0 + wn + j * 16 + l15 - 2048;
#pragma unroll
                for (int i = 0; i < AI; ++i) {
                    const int srow = m0 + wm + i * 16 + quad * 4;
                    const unsigned p0 = (unsigned)f2bf(acc[i][j][0]) |
                                        ((unsigned)f2bf(acc[i][j][1]) << 16);
                    const unsigned p1 = (unsigned)f2bf(acc[i][j][2]) |
                                        ((unsigned)f2bf(acc[i][j][3]) << 16);
                    const int pos = (srow & ~63) + ((((srow >> 3) & 7) ^ (hd & 7)) << 3) +
                                    (srow & 7);
                    *reinterpret_cast<uint2*>(&vout[(size_t)hd * SEQ_LEN + pos]) =
                        make_uint2(p0, p1);
                }
            }
        }
    }
}

// ---------------------------------------------------------------------------
// MFMA causal flash attention, no-max softmax, ALL staging via DMA (zero
// staging VALU; K and V^T arrive pre-swizzled from the producer GEMM).
// Block = 64 q-rows x 1 head (512 blocks). LPT pairing: first 256 dispatched
// blocks take qt=31..16 (heavy), second 256 take qt=0..15, so every CU's
// block pair sums to exactly 33 kv-tiles.
// 4 waves = 2(q-half of 32) x 2(kv-half of 32); K/V^T double-buffered, one
// barrier per kv-tile, DMA prefetch after barrier. Epilogue combines the two
// kv-half waves via LDS overlay. LDS 51 KB.
// ---------------------------------------------------------------------------
__global__ __launch_bounds__(256) void attn_mfma(const u16* __restrict__ Qb,
                                                 const u16* __restrict__ Kb,
                                                 const u16* __restrict__ Vg,
                                                 u16* __restrict__ O) {
    constexpr int PSTR = 40;
    __shared__ u16 SM[4096 + 8192 + 8192 + 4 * 32 * PSTR];  // 51200 B
    u16* Qs = SM;                  // [64 q][64 d]
    u16* Ks = SM + 4096;           // [2 buf][64 kv][64 d], d-groups ^ (s&7)
    u16* Vs = SM + 4096 + 8192;    // [2 buf][64 d][64 kv], kv-groups ^ (d&7)
    u16* Ps = SM + 4096 + 16384;   // [4 w][32 q][PSTR]
    // epilogue overlays (main-loop LDS dead by then):
    float* OredF = (float*)SM;                        // [64 q][68] fp32 (17408 B)
    float* LredF = (float*)(SM + 4096 + 8192 + 4096); // [64 q] fp32

    const int b = blockIdx.x;
    const int hb = b >> 4;
    // LPT pairing: CU gets blocks b and b+256 -> qt pair (31-hb, hb) sums 33
    const int qt = (hb < 16) ? (31 - hb) : (hb - 16);
    const int h = b & 15;
    const int q0 = qt * 64;

    const int t = threadIdx.x;
    const int lane = t & 63;
    const int quad = lane >> 4;
    const int l15 = lane & 15;
    const int w = t >> 6;
    const int wq = w >> 1;  // q half (32 rows)
    const int wk = w & 1;   // kv half (32 cols)

    const int drow = t >> 3;       // DMA: row within 32-row group
    const int doff = (t & 7) * 8;  // DMA: 16B lane offset (u16 units)

    auto stageK = [&](int buf, int j0) {
#pragma unroll
        for (int c = 0; c < 2; ++c)
            load_lds16(Kb + (size_t)(j0 + c * 32 + drow) * DIM + h * DHEAD + doff,
                       &Ks[buf * 4096 + c * 2048 + t * 8]);
    };
    auto stageV = [&](int buf, int j0) {
#pragma unroll
        for (int c = 0; c < 2; ++c)
            load_lds16(Vg + (size_t)(h * DHEAD + c * 32 + drow) * SEQ_LEN + j0 + doff,
                       &Vs[buf * 4096 + c * 2048 + t * 8]);
    };

    // ---- prologue: stage Q, K0, V0 ----
#pragma unroll
    for (int c = 0; c < 2; ++c)
        load_lds16(Qb + (size_t)(q0 + c * 32 + drow) * DIM + h * DHEAD + doff,
                   &Qs[c * 2048 + t * 8]);
    stageK(0, 0);
    stageV(0, 0);
    __syncthreads();  // all prologue DMA drained

    bf16x8 qf[2][2];
#pragma unroll
    for (int qq = 0; qq < 2; ++qq)
#pragma unroll
        for (int dc = 0; dc < 2; ++dc)
            qf[qq][dc] = *reinterpret_cast<const bf16x8*>(
                &Qs[(wq * 32 + qq * 16 + l15) * 64 + dc * 32 + quad * 8]);

    f32x4 oacc[2][4] = {};
    float lsum[2][4] = {};
    u16* Pw = Ps + w * 32 * PSTR;
    constexpr float SCL = 0.18033688f;  // (1/8)*log2(e)

    for (int jt = 0; jt <= qt; ++jt) {
        const int cur = jt & 1, nxt = cur ^ 1;
        if (jt > 0) __syncthreads();  // buf[cur] DMA drained; buf[nxt] readers done
        if (jt < qt) {                // prefetch next tile right after barrier
            stageK(nxt, (jt + 1) * 64);
            stageV(nxt, (jt + 1) * 64);
        }

        // ---- S = Q @ K^T (wave: 32 q x 32 kv) ----
        f32x4 sacc[2][2] = {};
#pragma unroll
        for (int nn = 0; nn < 2; ++nn)
#pragma unroll
            for (int dc = 0; dc < 2; ++dc) {
                const bf16x8 kf = *reinterpret_cast<const bf16x8*>(
                    &Ks[cur * 4096 + (wk * 32 + nn * 16 + l15) * 64 +
                        (((dc * 4 + quad) ^ (l15 & 7)) << 3)]);
#pragma unroll
                for (int qq = 0; qq < 2; ++qq)
                    sacc[qq][nn] =
                        __builtin_amdgcn_mfma_f32_16x16x32_bf16(qf[qq][dc], kf, sacc[qq][nn], 0, 0, 0);
            }

        // ---- no-max softmax; P truncated to bf16 into per-wave LDS ----
        const bool diag = (jt == qt);
#pragma unroll
        for (int qq = 0; qq < 2; ++qq)
#pragma unroll
            for (int r = 0; r < 4; ++r) {
                const int rowl = wq * 32 + qq * 16 + quad * 4 + r;
                float p0 = sacc[qq][0][r] * SCL, p1 = sacc[qq][1][r] * SCL;
                if (diag) {
                    if (wk * 32 + l15 > rowl) p0 = -1e30f;
                    if (wk * 32 + 16 + l15 > rowl) p1 = -1e30f;
                }
                p0 = exp2f(p0);
                p1 = exp2f(p1);
                lsum[qq][r] += p0 + p1;
                const int pr = (qq * 16 + quad * 4 + r) * PSTR;
                Pw[pr + l15] = (u16)(__float_as_uint(p0) >> 16);
                Pw[pr + 16 + l15] = (u16)(__float_as_uint(p1) >> 16);
            }

        // ---- O += P @ V (per-wave Ps; wave's 32-kv slice of V^T) ----
#pragma unroll
        for (int qq = 0; qq < 2; ++qq) {
            const bf16x8 pf =
                *reinterpret_cast<const bf16x8*>(&Pw[(qq * 16 + l15) * PSTR + quad * 8]);
#pragma unroll
            for (int nd = 0; nd < 4; ++nd) {
                const bf16x8 vf = *reinterpret_cast<const bf16x8*>(
                    &Vs[cur * 4096 + (nd * 16 + l15) * 64 +
                        (((wk * 4 + quad) ^ (l15 & 7)) << 3)]);
                oacc[qq][nd] =
                    __builtin_amdgcn_mfma_f32_16x16x32_bf16(pf, vf, oacc[qq][nd], 0, 0, 0);
            }
        }
    }

    // ---- epilogue: reduce lsum over 16 kv-lanes (per wave) ----
#pragma unroll
    for (int qq = 0; qq < 2; ++qq)
#pragma unroll
        for (int r = 0; r < 4; ++r) {
            float l = lsum[qq][r];
#pragma unroll
            for (int off = 1; off < 16; off <<= 1) l += __shfl_xor(l, off, 64);
            lsum[qq][r] = l;
        }
    __syncthreads();  // main-loop LDS dead; overlays safe
    // wk=1 waves publish their kv-half partials (O and l) to LDS
    if (wk == 1) {
#pragma unroll
        for (int qq = 0; qq < 2; ++qq)
#pragma unroll
            for (int r = 0; r < 4; ++r) {
                const int rowl = wq * 32 + qq * 16 + quad * 4 + r;
                if (l15 == 0) LredF[rowl] = lsum[qq][r];
#pragma unroll
                for (int nd = 0; nd < 4; ++nd)
                    OredF[rowl * 68 + nd * 16 + l15] = oacc[qq][nd][r];
            }
    }
    __syncthreads();
    // wk=0 waves combine, normalize (combined l > 0 always), write bf16
    if (wk == 0) {
#pragma unroll
        for (int qq = 0; qq < 2; ++qq)
#pragma unroll
            for (int r = 0; r < 4; ++r) {
                const int rowl = wq * 32 + qq * 16 + quad * 4 + r;
                const float inv = 1.0f / (lsum[qq][r] + LredF[rowl]);
                const int row = q0 + rowl;
#pragma unroll
                for (int nd = 0; nd < 4; ++nd)
                    O[(size_t)row * DIM + h * DHEAD + nd * 16 + l15] =
                        f2bf((oacc[qq][nd][r] + OredF[rowl * 68 + nd * 16 + l15]) * inv);
            }
    }
}

// ---------------------------------------------------------------------------
extern "C" void kernel_launch(void* const* d_in, const int* in_sizes, int n_in,
                              void* d_out, int out_size, void* d_ws, size_t ws_size,
                              hipStream_t stream) {
    const float* x = (const float*)d_in[0];     // [2048,1024]
    const float* Wqkv = (const float*)d_in[1];  // [1024,3072]
    const float* Wout = (const float*)d_in[2];  // [1024,1024]
    const float* bias = (const float*)d_in[3];  // [1024]
    float* out = (float*)d_out;

    char* ws = (char*)d_ws;
    u16* xb = (u16*)ws;                     // 4 MB
    u16* Wqkvt = (u16*)(ws + (4u << 20));   // 6 MB  [3072,1024]
    u16* Woutt = (u16*)(ws + (10u << 20));  // 2 MB  [1024,1024]
    u16* Qb = (u16*)(ws + (12u << 20));     // 4 MB  [2048,1024]
    u16* Kb = (u16*)(ws + (16u << 20));     // 4 MB  [2048,1024] swizzled
    u16* Vg = (u16*)(ws + (20u << 20));     // 4 MB  [1024,2048] V^T swizzled
    u16* Ob = (u16*)(ws + (24u << 20));     // 4 MB  [2048,1024]

    // fused prep: cast x + transpose Wqkv + transpose Wout
    prep_k<<<dim3(6144), 256, 0, stream>>>(x, Wqkv, Wout, xb, Wqkvt, Woutt);

    // qkv = x @ Wqkv, split-layout epilogue (Q / K-swizzled / V^T-swizzled)
    // BK=64: 16 K-iters (half the barrier drains of BK=32), 48 KB LDS, 3/CU
    gemm_bf16<0, 128, 64, 64><<<dim3(QKV_LD / 64, SEQ_LEN / 128), 256, 0, stream>>>(
        xb, Wqkvt, nullptr, Qb, Kb, Vg, SEQ_LEN, QKV_LD, DIM);

    // causal attention: 512 blocks, LPT-paired (each CU pair sums 33 tiles)
    attn_mfma<<<dim3(32 * NHEAD), 256, 0, stream>>>(Qb, Kb, Vg, Ob);

    // out = O @ Wout + bias (fp32): 64x64x64 tiles -> 512 blocks
    gemm_bf16<1, 64, 64, 64><<<dim3(DIM / 64, SEQ_LEN / 64), 256, 0, stream>>>(
        Ob, Woutt, bias, out, nullptr, nullptr, SEQ_LEN, DIM, DIM);
}